// Round 13
// baseline (418.731 us; speedup 1.0000x reference)
//
#include <hip/hip_runtime.h>

#define NN 8192
#define FIN 512
#define FOUT 64
#define LRELU_ALPHA 0.2f
#define LOG2E 1.4426950408889634f

typedef __attribute__((ext_vector_type(4))) float f32x4;
typedef __attribute__((ext_vector_type(4))) int i32x4;
typedef __attribute__((ext_vector_type(8))) __bf16 bf16x8;

#if __has_builtin(__builtin_amdgcn_exp2f)
#define EXP2F(x) __builtin_amdgcn_exp2f(x)
#else
#define EXP2F(x) exp2f(x)
#endif

// Kernel A: round-11 VERBATIM (best passing build, 405.4 µs; R12's pi-store
// reverted). Wh stored in MFMA B-fragment-linear order Wpk:
// Wpk[((c*4+fb)*64 + qq*16 + rr)*8 + j] = Wh[c*32+qq*8+j][fb*16+rr].
__global__ __launch_bounds__(256) void gat_wh(
    const float* __restrict__ x, const float* __restrict__ W,
    const float* __restrict__ A,
    __bf16* __restrict__ Wpk, float* __restrict__ s1, float* __restrict__ s2)
{
    const int wid  = (blockIdx.x * 256 + threadIdx.x) >> 6;
    const int lane = threadIdx.x & 63;
    const int cg   = lane & 15;
    const int kh   = lane >> 4;
    const int row0 = wid * 4;

    f32x4 acc[4];
    #pragma unroll
    for (int r_ = 0; r_ < 4; ++r_) acc[r_] = (f32x4){0.f, 0.f, 0.f, 0.f};

    const float* xb   = x + (size_t)row0 * FIN + kh * 128;
    const float* wcol = W + cg * 4 + (size_t)kh * 128 * FOUT;

    #pragma unroll 2
    for (int k = 0; k < 128; k += 4) {
        f32x4 wv[4];
        #pragma unroll
        for (int u = 0; u < 4; ++u)
            wv[u] = *reinterpret_cast<const f32x4*>(wcol + (size_t)(k + u) * FOUT);
        #pragma unroll
        for (int r_ = 0; r_ < 4; ++r_) {
            f32x4 xv = *reinterpret_cast<const f32x4*>(xb + (size_t)r_ * FIN + k);
            acc[r_] += xv[0] * wv[0];
            acc[r_] += xv[1] * wv[1];
            acc[r_] += xv[2] * wv[2];
            acc[r_] += xv[3] * wv[3];
        }
    }

    #pragma unroll
    for (int r_ = 0; r_ < 4; ++r_) {
        #pragma unroll
        for (int u = 0; u < 4; ++u) {
            acc[r_][u] += __shfl_xor(acc[r_][u], 16);
            acc[r_][u] += __shfl_xor(acc[r_][u], 32);
        }
    }

    f32x4 a1v = *reinterpret_cast<const f32x4*>(A + cg * 4);
    f32x4 a2v = *reinterpret_cast<const f32x4*>(A + FOUT + cg * 4);
    #pragma unroll
    for (int r_ = 0; r_ < 4; ++r_) {
        float s1p = acc[r_][0]*a1v[0] + acc[r_][1]*a1v[1] + acc[r_][2]*a1v[2] + acc[r_][3]*a1v[3];
        float s2p = acc[r_][0]*a2v[0] + acc[r_][1]*a2v[1] + acc[r_][2]*a2v[2] + acc[r_][3]*a2v[3];
        #pragma unroll
        for (int off = 1; off < 16; off <<= 1) {
            s1p += __shfl_xor(s1p, off);
            s2p += __shfl_xor(s2p, off);
        }
        if (lane == 0) { s1[row0 + r_] = s1p; s2[row0 + r_] = s2p; }
    }

    {
        const int fb = cg >> 2;
        const int rr = ((cg & 3) << 2) + kh;
        #pragma unroll
        for (int r_ = 0; r_ < 4; ++r_) {
            const int node = row0 + r_;
            const int c    = node >> 5;
            const int qq   = (node >> 3) & 3;
            const int j    = node & 7;
            Wpk[((size_t)((c << 2) + fb) << 9) + (qq << 7) + (rr << 3) + j]
                = (__bf16)acc[r_][kh];
        }
    }
}

// Kernel B: 32-ROW blocks — the first change that reduces per-CU TCP bytes
// (the one quantity invariant across R3/R7/R8/R10/R11/R12's nulls).
// 8 waves x 1024-col strip; each wave computes TWO 16-row MFMA groups (A/B)
// that SHARE the same B-fragments: per half, 4 adj + 4 Wh loads feed 1024
// output elements (vs 6 loads/512 before) -> Wh chip traffic 512->256 MB,
// per-CU bytes 3->2 MB. Per-element arithmetic bit-identical to R11.
__global__ __launch_bounds__(512) void gat_attn(
    const int* __restrict__ adj, const __bf16* __restrict__ Wpk,
    const float* __restrict__ s1g, const float* __restrict__ s2g,
    const float* __restrict__ bias, float* __restrict__ out)
{
    __shared__ float s2l[NN];             // s2 * log2(e)  (32 KB)
    __shared__ float red[8];
    __shared__ float ol[8][32];
    __shared__ float oacc[8][32][FOUT];   // 64 KB

    const int tid  = threadIdx.x;
    const int w    = tid >> 6;            // wave 0..7 -> col strip w*1024
    const int lane = tid & 63;
    const int r    = lane & 15;           // MFMA A-row / C-col
    const int q    = lane >> 4;           // k-quad
    const int row0 = blockIdx.x * 32;

    float mx = -3.0e38f;
    for (int i = tid; i < NN / 4; i += 512) {
        f32x4 v = reinterpret_cast<const f32x4*>(s2g)[i];
        v *= LOG2E;
        reinterpret_cast<f32x4*>(s2l)[i] = v;
        mx = fmaxf(mx, fmaxf(fmaxf(v[0], v[1]), fmaxf(v[2], v[3])));
    }
    #pragma unroll
    for (int off = 1; off < 64; off <<= 1)
        mx = fmaxf(mx, __shfl_xor(mx, off));
    if (lane == 0) red[w] = mx;
    __syncthreads();
    float s2maxl = red[0];
    #pragma unroll
    for (int i = 1; i < 8; ++i) s2maxl = fmaxf(s2maxl, red[i]);

    // per-row-group constants (fixed-M softmax, lrelu folded; log2 domain)
    const float s1A = s1g[row0 + r] * LOG2E;
    const float s1B = s1g[row0 + 16 + r] * LOG2E;
    const float tMA = s1A + s2maxl;
    const float tMB = s1B + s2maxl;
    const float MlA = fmaxf(tMA, LRELU_ALPHA * tMA);
    const float MlB = fmaxf(tMB, LRELU_ALPHA * tMB);
    const float c1A = s1A - MlA, c2A = LRELU_ALPHA * s1A - MlA;
    const float c1B = s1B - MlB, c2B = LRELU_ALPHA * s1B - MlB;

    const __bf16 oneb = (__bf16)1.0f;
    const bf16x8 onesv = {oneb, oneb, oneb, oneb, oneb, oneb, oneb, oneb};

    f32x4 accA0 = {0,0,0,0}, accA1 = {0,0,0,0}, accA2 = {0,0,0,0}, accA3 = {0,0,0,0};
    f32x4 accB0 = {0,0,0,0}, accB1 = {0,0,0,0}, accB2 = {0,0,0,0}, accB3 = {0,0,0,0};
    f32x4 accLA = {0,0,0,0}, accLB = {0,0,0,0};

    const int*    adjpA = adj + (size_t)(row0 + r) * NN + (w << 10) + (q << 3);
    const int*    adjpB = adjpA + (size_t)16 * NN;
    const __bf16* wq    = Wpk + ((size_t)w << 16) + ((size_t)lane << 3);
    const float*  s2p_  = s2l + (w << 10) + (q << 3);

    for (int h = 0; h < 32; ++h) {                    // 32 cols per half
        const int jc = h << 5;
        const __bf16* ph = wq + ((size_t)h << 11);    // chunk stride 2048 elems

        i32x4 avA0 = *reinterpret_cast<const i32x4*>(adjpA + jc);
        i32x4 avA1 = *reinterpret_cast<const i32x4*>(adjpA + jc + 4);
        i32x4 avB0 = *reinterpret_cast<const i32x4*>(adjpB + jc);
        i32x4 avB1 = *reinterpret_cast<const i32x4*>(adjpB + jc + 4);
        bf16x8 b0 = *reinterpret_cast<const bf16x8*>(ph);
        bf16x8 b1 = *reinterpret_cast<const bf16x8*>(ph + 512);
        bf16x8 b2 = *reinterpret_cast<const bf16x8*>(ph + 1024);
        bf16x8 b3 = *reinterpret_cast<const bf16x8*>(ph + 1536);
        f32x4 s2a = *reinterpret_cast<const f32x4*>(s2p_ + jc);
        f32x4 s2c = *reinterpret_cast<const f32x4*>(s2p_ + jc + 4);

        bf16x8 afA, afB;
        #pragma unroll
        for (int i = 0; i < 4; ++i) {
            float gA0 = fmaxf(c1A + s2a[i], fmaf(LRELU_ALPHA, s2a[i], c2A));
            gA0 = (avA0[i] > 0) ? gA0 : -3.0e38f;
            afA[i] = (__bf16)EXP2F(gA0);
            float gA1 = fmaxf(c1A + s2c[i], fmaf(LRELU_ALPHA, s2c[i], c2A));
            gA1 = (avA1[i] > 0) ? gA1 : -3.0e38f;
            afA[i + 4] = (__bf16)EXP2F(gA1);
            float gB0 = fmaxf(c1B + s2a[i], fmaf(LRELU_ALPHA, s2a[i], c2B));
            gB0 = (avB0[i] > 0) ? gB0 : -3.0e38f;
            afB[i] = (__bf16)EXP2F(gB0);
            float gB1 = fmaxf(c1B + s2c[i], fmaf(LRELU_ALPHA, s2c[i], c2B));
            gB1 = (avB1[i] > 0) ? gB1 : -3.0e38f;
            afB[i + 4] = (__bf16)EXP2F(gB1);
        }
        accA0 = __builtin_amdgcn_mfma_f32_16x16x32_bf16(afA, b0, accA0, 0, 0, 0);
        accA1 = __builtin_amdgcn_mfma_f32_16x16x32_bf16(afA, b1, accA1, 0, 0, 0);
        accA2 = __builtin_amdgcn_mfma_f32_16x16x32_bf16(afA, b2, accA2, 0, 0, 0);
        accA3 = __builtin_amdgcn_mfma_f32_16x16x32_bf16(afA, b3, accA3, 0, 0, 0);
        accLA = __builtin_amdgcn_mfma_f32_16x16x32_bf16(afA, onesv, accLA, 0, 0, 0);
        accB0 = __builtin_amdgcn_mfma_f32_16x16x32_bf16(afB, b0, accB0, 0, 0, 0);
        accB1 = __builtin_amdgcn_mfma_f32_16x16x32_bf16(afB, b1, accB1, 0, 0, 0);
        accB2 = __builtin_amdgcn_mfma_f32_16x16x32_bf16(afB, b2, accB2, 0, 0, 0);
        accB3 = __builtin_amdgcn_mfma_f32_16x16x32_bf16(afB, b3, accB3, 0, 0, 0);
        accLB = __builtin_amdgcn_mfma_f32_16x16x32_bf16(afB, onesv, accLB, 0, 0, 0);
    }

    if (r == 0) {
        #pragma unroll
        for (int reg = 0; reg < 4; ++reg) {
            ol[w][(q << 2) + reg]      = accLA[reg];
            ol[w][16 + (q << 2) + reg] = accLB[reg];
        }
    }
    #pragma unroll
    for (int reg = 0; reg < 4; ++reg) {
        oacc[w][(q << 2) + reg][0 * 16 + r] = accA0[reg];
        oacc[w][(q << 2) + reg][1 * 16 + r] = accA1[reg];
        oacc[w][(q << 2) + reg][2 * 16 + r] = accA2[reg];
        oacc[w][(q << 2) + reg][3 * 16 + r] = accA3[reg];
        oacc[w][16 + (q << 2) + reg][0 * 16 + r] = accB0[reg];
        oacc[w][16 + (q << 2) + reg][1 * 16 + r] = accB1[reg];
        oacc[w][16 + (q << 2) + reg][2 * 16 + r] = accB2[reg];
        oacc[w][16 + (q << 2) + reg][3 * 16 + r] = accB3[reg];
    }
    __syncthreads();

    for (int o = tid; o < 32 * FOUT; o += 512) {
        const int rr = o >> 6;
        const int f  = o & 63;
        float L = 0.f, O = 0.f;
        #pragma unroll
        for (int w2 = 0; w2 < 8; ++w2) {
            L += ol[w2][rr];
            O += oacc[w2][rr][f];
        }
        out[(size_t)(row0 + rr) * FOUT + f] = O / L + bias[f];
    }
}

extern "C" void kernel_launch(void* const* d_in, const int* in_sizes, int n_in,
                              void* d_out, int out_size, void* d_ws, size_t ws_size,
                              hipStream_t stream)
{
    const float* x    = (const float*)d_in[0];
    const int*   adj  = (const int*)d_in[1];
    const float* W    = (const float*)d_in[2];
    const float* bias = (const float*)d_in[3];
    const float* A    = (const float*)d_in[4];
    float* out = (float*)d_out;

    // workspace: Wpk (1 MB) | s1 (32 KB) | s2 (32 KB)
    char* ws = (char*)d_ws;
    __bf16* Wpk = (__bf16*)ws;
    float*  s1  = (float*)(ws + (size_t)FOUT * NN * sizeof(__bf16));
    float*  s2  = s1 + NN;

    gat_wh<<<dim3(512), dim3(256), 0, stream>>>(x, W, A, Wpk, s1, s2);
    gat_attn<<<dim3(NN / 32), dim3(512), 0, stream>>>(adj, Wpk, s1, s2, bias, out);
}

// Round 14
// 412.913 us; speedup vs baseline: 1.0141x; 1.0141x over previous
//
#include <hip/hip_runtime.h>

#define NN 8192
#define FIN 512
#define FOUT 64
#define LRELU_ALPHA 0.2f
#define LOG2E 1.4426950408889634f

typedef __attribute__((ext_vector_type(4))) float f32x4;
typedef __attribute__((ext_vector_type(4))) int i32x4;
typedef __attribute__((ext_vector_type(8))) __bf16 bf16x8;

#if __has_builtin(__builtin_amdgcn_exp2f)
#define EXP2F(x) __builtin_amdgcn_exp2f(x)
#else
#define EXP2F(x) exp2f(x)
#endif

// FINAL = round-11 build (best verified: 405.4 µs, absmax 0.0078125).
// Session ledger (456.2 baseline -> 405.4):
//   -19  fixed-M softmax (exact: softmax is shift-invariant; M_i = lrelu(s1_i+max s2))
//   -27  gat_wh 4-rows/wave W-reuse (W L2 traffic 1 GB -> 256 MB)
//   -3.4 fragment-linear Wpk (contiguous MFMA B-operand loads)
//   ~0   ones-MFMA row-sum (VALU trim, kept)
// Falsified attn theories (all reverted): occupancy split (R3), manual 2-deep
// pipeline (R7 +22), LDS burst staging (R8 +44), bitmask adj (R10 +54 incl.
// pack), pi line-split (R12 +7), 32-row blocks (R13 +13).
// Remaining ~75 µs attn = ADDITIVE latency floor: adj HBM ~21 (poison fill
// evicts half of L3 each iter; FETCH=135 MB measured) + L2 Wh ~15 + TCP
// line-processing ~25 + VALU ~7 + MFMA ~3, non-overlapped at the 2-waves/SIMD
// cap fixed by grid = 2 blocks/CU.

// Kernel A: Wh = x@W, s1/s2 = Wh@a1/a2; Wh stored in MFMA B-fragment-linear
// order: Wpk[((c*4+fb)*64 + qq*16 + rr)*8 + j] = Wh[c*32+qq*8+j][fb*16+rr].
__global__ __launch_bounds__(256) void gat_wh(
    const float* __restrict__ x, const float* __restrict__ W,
    const float* __restrict__ A,
    __bf16* __restrict__ Wpk, float* __restrict__ s1, float* __restrict__ s2)
{
    const int wid  = (blockIdx.x * 256 + threadIdx.x) >> 6;
    const int lane = threadIdx.x & 63;
    const int cg   = lane & 15;
    const int kh   = lane >> 4;
    const int row0 = wid * 4;

    f32x4 acc[4];
    #pragma unroll
    for (int r_ = 0; r_ < 4; ++r_) acc[r_] = (f32x4){0.f, 0.f, 0.f, 0.f};

    const float* xb   = x + (size_t)row0 * FIN + kh * 128;
    const float* wcol = W + cg * 4 + (size_t)kh * 128 * FOUT;

    #pragma unroll 2
    for (int k = 0; k < 128; k += 4) {
        f32x4 wv[4];
        #pragma unroll
        for (int u = 0; u < 4; ++u)
            wv[u] = *reinterpret_cast<const f32x4*>(wcol + (size_t)(k + u) * FOUT);
        #pragma unroll
        for (int r_ = 0; r_ < 4; ++r_) {
            f32x4 xv = *reinterpret_cast<const f32x4*>(xb + (size_t)r_ * FIN + k);
            acc[r_] += xv[0] * wv[0];
            acc[r_] += xv[1] * wv[1];
            acc[r_] += xv[2] * wv[2];
            acc[r_] += xv[3] * wv[3];
        }
    }

    // butterfly over lane bits 4,5: ALL lanes now hold the full-K dot products
    #pragma unroll
    for (int r_ = 0; r_ < 4; ++r_) {
        #pragma unroll
        for (int u = 0; u < 4; ++u) {
            acc[r_][u] += __shfl_xor(acc[r_][u], 16);
            acc[r_][u] += __shfl_xor(acc[r_][u], 32);
        }
    }

    f32x4 a1v = *reinterpret_cast<const f32x4*>(A + cg * 4);
    f32x4 a2v = *reinterpret_cast<const f32x4*>(A + FOUT + cg * 4);
    #pragma unroll
    for (int r_ = 0; r_ < 4; ++r_) {
        float s1p = acc[r_][0]*a1v[0] + acc[r_][1]*a1v[1] + acc[r_][2]*a1v[2] + acc[r_][3]*a1v[3];
        float s2p = acc[r_][0]*a2v[0] + acc[r_][1]*a2v[1] + acc[r_][2]*a2v[2] + acc[r_][3]*a2v[3];
        #pragma unroll
        for (int off = 1; off < 16; off <<= 1) {
            s1p += __shfl_xor(s1p, off);
            s2p += __shfl_xor(s2p, off);
        }
        if (lane == 0) { s1[row0 + r_] = s1p; s2[row0 + r_] = s2p; }
    }

    // permuted store: lane (cg,kh) stores feat = cg*4 + kh for its 4 nodes.
    {
        const int fb = cg >> 2;
        const int rr = ((cg & 3) << 2) + kh;
        #pragma unroll
        for (int r_ = 0; r_ < 4; ++r_) {
            const int node = row0 + r_;
            const int c    = node >> 5;
            const int qq   = (node >> 3) & 3;
            const int j    = node & 7;
            Wpk[((size_t)((c << 2) + fb) << 9) + (qq << 7) + (rr << 3) + j]
                = (__bf16)acc[r_][kh];
        }
    }
}

// Kernel B: fixed-M masked-softmax attention. Direct adj loads; B-operands
// from fragment-linear Wpk (1 KB contiguous per wave, imm offsets); row-sum
// via ones-MFMA on the ~2%-utilized matrix pipe; plain-sum cross-wave merge.
__global__ __launch_bounds__(256) void gat_attn(
    const int* __restrict__ adj, const __bf16* __restrict__ Wpk,
    const float* __restrict__ s1g, const float* __restrict__ s2g,
    const float* __restrict__ bias, float* __restrict__ out)
{
    __shared__ float s2l[NN];             // s2 * log2(e)
    __shared__ float red[4];
    __shared__ float ol[4][16];
    __shared__ float oacc[4][16][FOUT];

    const int tid  = threadIdx.x;
    const int w    = tid >> 6;
    const int lane = tid & 63;
    const int r    = lane & 15;           // MFMA A-row / C-col
    const int q    = lane >> 4;           // k-quad
    const int row0 = blockIdx.x * 16;

    float mx = -3.0e38f;
    for (int i = tid; i < NN / 4; i += 256) {
        f32x4 v = reinterpret_cast<const f32x4*>(s2g)[i];
        v *= LOG2E;
        reinterpret_cast<f32x4*>(s2l)[i] = v;
        mx = fmaxf(mx, fmaxf(fmaxf(v[0], v[1]), fmaxf(v[2], v[3])));
    }
    #pragma unroll
    for (int off = 1; off < 64; off <<= 1)
        mx = fmaxf(mx, __shfl_xor(mx, off));
    if (lane == 0) red[w] = mx;
    __syncthreads();
    const float s2maxl = fmaxf(fmaxf(red[0], red[1]), fmaxf(red[2], red[3]));

    const float s1l = s1g[row0 + r] * LOG2E;
    const float tM  = s1l + s2maxl;
    const float Ml  = fmaxf(tM, LRELU_ALPHA * tM);   // lrelu in log2 domain
    const float c1  = s1l - Ml;
    const float c2  = LRELU_ALPHA * s1l - Ml;

    const __bf16 oneb = (__bf16)1.0f;
    const bf16x8 onesv = {oneb, oneb, oneb, oneb, oneb, oneb, oneb, oneb};

    f32x4 acc0 = {0,0,0,0}, acc1 = {0,0,0,0}, acc2 = {0,0,0,0}, acc3 = {0,0,0,0};
    f32x4 accL = {0,0,0,0};

    const int*    adjp = adj + (size_t)(row0 + r) * NN + (w << 11) + (q << 3);
    // fragment-linear Wh: per-wave strip = 256KB (1<<17 elements), per-lane 16B
    const __bf16* wq   = Wpk + ((size_t)w << 17) + ((size_t)lane << 3);
    const float*  s2p_ = s2l + (w << 11) + (q << 3);

    for (int it = 0; it < 32; ++it) {                 // 64 cols per iteration
        const int j0 = it << 6;
        #pragma unroll
        for (int c = 0; c < 2; ++c) {
            const int jc = j0 + (c << 5);
            const __bf16* ph = wq + ((size_t)(jc >> 5) << 11);   // chunk*2048 elems
            i32x4 av0 = *reinterpret_cast<const i32x4*>(adjp + jc);
            i32x4 av1 = *reinterpret_cast<const i32x4*>(adjp + jc + 4);
            bf16x8 b0 = *reinterpret_cast<const bf16x8*>(ph);
            bf16x8 b1 = *reinterpret_cast<const bf16x8*>(ph + 512);
            bf16x8 b2 = *reinterpret_cast<const bf16x8*>(ph + 1024);
            bf16x8 b3 = *reinterpret_cast<const bf16x8*>(ph + 1536);
            f32x4 s2a = *reinterpret_cast<const f32x4*>(s2p_ + jc);
            f32x4 s2c = *reinterpret_cast<const f32x4*>(s2p_ + jc + 4);

            bf16x8 af;
            #pragma unroll
            for (int i = 0; i < 4; ++i) {
                float g0 = fmaxf(c1 + s2a[i], fmaf(LRELU_ALPHA, s2a[i], c2));
                g0 = (av0[i] > 0) ? g0 : -3.0e38f;     // masked -> exp2 -> 0
                af[i] = (__bf16)EXP2F(g0);
                float g1 = fmaxf(c1 + s2c[i], fmaf(LRELU_ALPHA, s2c[i], c2));
                g1 = (av1[i] > 0) ? g1 : -3.0e38f;
                af[i + 4] = (__bf16)EXP2F(g1);
            }
            acc0 = __builtin_amdgcn_mfma_f32_16x16x32_bf16(af, b0, acc0, 0, 0, 0);
            acc1 = __builtin_amdgcn_mfma_f32_16x16x32_bf16(af, b1, acc1, 0, 0, 0);
            acc2 = __builtin_amdgcn_mfma_f32_16x16x32_bf16(af, b2, acc2, 0, 0, 0);
            acc3 = __builtin_amdgcn_mfma_f32_16x16x32_bf16(af, b3, acc3, 0, 0, 0);
            accL = __builtin_amdgcn_mfma_f32_16x16x32_bf16(af, onesv, accL, 0, 0, 0);
        }
    }

    // l lives in accL: C row = q*4+reg, identical across cols (B uniform)
    if (r == 0) {
        #pragma unroll
        for (int reg = 0; reg < 4; ++reg) ol[w][(q << 2) + reg] = accL[reg];
    }
    #pragma unroll
    for (int reg = 0; reg < 4; ++reg) {
        oacc[w][(q << 2) + reg][0 * 16 + r] = acc0[reg];
        oacc[w][(q << 2) + reg][1 * 16 + r] = acc1[reg];
        oacc[w][(q << 2) + reg][2 * 16 + r] = acc2[reg];
        oacc[w][(q << 2) + reg][3 * 16 + r] = acc3[reg];
    }
    __syncthreads();

    for (int o = tid; o < 16 * FOUT; o += 256) {
        const int rr = o >> 6;
        const int f  = o & 63;
        const float L = ol[0][rr] + ol[1][rr] + ol[2][rr] + ol[3][rr];
        const float O = oacc[0][rr][f] + oacc[1][rr][f] + oacc[2][rr][f] + oacc[3][rr][f];
        out[(size_t)(row0 + rr) * FOUT + f] = O / L + bias[f];
    }
}

extern "C" void kernel_launch(void* const* d_in, const int* in_sizes, int n_in,
                              void* d_out, int out_size, void* d_ws, size_t ws_size,
                              hipStream_t stream)
{
    const float* x    = (const float*)d_in[0];
    const int*   adj  = (const int*)d_in[1];
    const float* W    = (const float*)d_in[2];
    const float* bias = (const float*)d_in[3];
    const float* A    = (const float*)d_in[4];
    float* out = (float*)d_out;

    // workspace: Wpk (1 MB) | s1 (32 KB) | s2 (32 KB)
    char* ws = (char*)d_ws;
    __bf16* Wpk = (__bf16*)ws;
    float*  s1  = (float*)(ws + (size_t)FOUT * NN * sizeof(__bf16));
    float*  s2  = s1 + NN;

    gat_wh<<<dim3(512), dim3(256), 0, stream>>>(x, W, A, Wpk, s1, s2);
    gat_attn<<<dim3(NN / 16), dim3(256), 0, stream>>>(adj, Wpk, s1, s2, bias, out);
}